// Round 8
// baseline (428.656 us; speedup 1.0000x reference)
//
#include <hip/hip_runtime.h>

// ExternalNeighbors: per-pair displacement + periodic shift + cutoff mask.
// Outputs (concatenated flat, all float32):
//   [0N..1N) dist | [1N..2N) pair_first | [2N..3N) pair_second
//   [3N..6N) paircoord (N,3) | [6N..7N) mask
//
// Ledger: v2 231us -> v3 181 (1-hop float4 table) -> v4 169 (NT st)
//   -> v5 251 REGRESS (strided NT = partial lines, WRITE 460MB)
//   -> v6 153 (plain ld + NT st + LDS-transposed pc: WRITE exactly 229376KB)
// v7: persistent grid-stride + wave-private LDS staging WITHOUT
// __syncthreads (wave_barrier only) -> no per-batch vmcnt(0) drain, loop
// overlap of next loads/gathers with in-flight NT stores.

typedef float f32x4 __attribute__((ext_vector_type(4)));
typedef int   i32x4 __attribute__((ext_vector_type(4)));

#define HARD_DIST_CUTOFF 2.0f

__global__ __launch_bounds__(256) void build_gather_table(
    const float* __restrict__ coords,      // n_real * 3
    const int*   __restrict__ real_atoms,  // n_real
    f32x4* __restrict__ tab,               // n_real (padded xyz_)
    int n_real)
{
    const int i = blockIdx.x * blockDim.x + threadIdx.x;
    if (i < n_real) {
        const int a = real_atoms[i];
        const float* c = coords + 3 * (size_t)a;
        f32x4 v;
        v.x = c[0]; v.y = c[1]; v.z = c[2]; v.w = 0.0f;
        tab[i] = v;  // plain store: keep table cache-resident for the gathers
    }
}

__global__ __launch_bounds__(256) void external_neighbors_v7(
    const f32x4* __restrict__ tab,          // n_real pre-gathered coords
    const int*   __restrict__ shifts,       // n_pairs * 3
    const float* __restrict__ cell,         // 9
    const int*   __restrict__ pair_first,   // n_pairs
    const int*   __restrict__ pair_second,  // n_pairs
    float* __restrict__ out,
    int n_pairs)
{
    __shared__ float lds_pc[4][768];  // per-WAVE 3KB staging for paircoord

    const float c00 = cell[0], c01 = cell[1], c02 = cell[2];
    const float c10 = cell[3], c11 = cell[4], c12 = cell[5];
    const float c20 = cell[6], c21 = cell[7], c22 = cell[8];

    const size_t N = (size_t)n_pairs;
    float* __restrict__ out_dist = out;
    float* __restrict__ out_pf   = out + N;
    float* __restrict__ out_ps   = out + 2 * N;
    float* __restrict__ out_pc   = out + 3 * N;
    float* __restrict__ out_mask = out + 6 * N;

    const int tid0   = blockIdx.x * blockDim.x + threadIdx.x;
    const int nthr   = gridDim.x * blockDim.x;
    const int nbatch = n_pairs >> 2;           // batches of 4 pairs
    const int wv     = threadIdx.x >> 6;
    const int lane   = threadIdx.x & 63;

    for (int b = tid0; b < nbatch; b += nthr) {
        const int base = b << 2;

        // ---- plain (cached) stream loads: inputs are L3-warm ----
        const i32x4 pf4 = *reinterpret_cast<const i32x4*>(pair_first  + base);
        const i32x4 ps4 = *reinterpret_cast<const i32x4*>(pair_second + base);
        const i32x4* sh = reinterpret_cast<const i32x4*>(shifts + 3 * (size_t)base);
        const i32x4 sA = sh[0], sB = sh[1], sC = sh[2];

        const int pf[4] = {pf4.x, pf4.y, pf4.z, pf4.w};
        const int ps[4] = {ps4.x, ps4.y, ps4.z, ps4.w};
        const int s0[4] = {sA.x, sA.w, sB.z, sC.y};
        const int s1[4] = {sA.y, sB.x, sB.w, sC.z};
        const int s2[4] = {sA.z, sB.y, sC.x, sC.w};

        // ---- 8 independent 16B gathers (cache-resident table) ----
        f32x4 A[4], B[4];
        #pragma unroll
        for (int k = 0; k < 4; ++k) A[k] = tab[pf[k]];
        #pragma unroll
        for (int k = 0; k < 4; ++k) B[k] = tab[ps[k]];

        // ---- compute ----
        f32x4 dist, pfo, pso, msk;
        float dxv[4], dyv[4], dzv[4];
        #pragma unroll
        for (int k = 0; k < 4; ++k) {
            const float f0 = (float)s0[k], f1 = (float)s1[k], f2 = (float)s2[k];
            const float dx = B[k].x - A[k].x + f0 * c00 + f1 * c10 + f2 * c20;
            const float dy = B[k].y - A[k].y + f0 * c01 + f1 * c11 + f2 * c21;
            const float dz = B[k].z - A[k].z + f0 * c02 + f1 * c12 + f2 * c22;
            const float d  = sqrtf(dx * dx + dy * dy + dz * dz);
            const bool  m  = d < HARD_DIST_CUTOFF;
            dist[k] = m ? d : 0.0f;
            pfo[k]  = m ? (float)pf[k] : -1.0f;
            pso[k]  = m ? (float)ps[k] : -1.0f;
            msk[k]  = m ? 1.0f : 0.0f;
            dxv[k]  = m ? dx : 0.0f;
            dyv[k]  = m ? dy : 0.0f;
            dzv[k]  = m ? dz : 0.0f;
        }

        // ---- coalesced NT stores (1KB wave bursts each) ----
        __builtin_nontemporal_store(dist, reinterpret_cast<f32x4*>(out_dist + base));
        __builtin_nontemporal_store(pfo,  reinterpret_cast<f32x4*>(out_pf   + base));
        __builtin_nontemporal_store(pso,  reinterpret_cast<f32x4*>(out_ps   + base));
        __builtin_nontemporal_store(msk,  reinterpret_cast<f32x4*>(out_mask + base));

        // ---- paircoord via wave-private LDS transpose (no block barrier) ----
        const int wfirst = b - lane;  // wave's first batch this iteration
        if (wfirst + 64 <= nbatch) {
            f32x4* myl = reinterpret_cast<f32x4*>(&lds_pc[wv][12 * lane]);
            myl[0] = (f32x4){dxv[0], dyv[0], dzv[0], dxv[1]};
            myl[1] = (f32x4){dyv[1], dzv[1], dxv[2], dyv[2]};
            myl[2] = (f32x4){dzv[2], dxv[3], dyv[3], dzv[3]};
            __builtin_amdgcn_wave_barrier();  // wave64 lockstep; lgkmcnt orders LDS
            float* pcw = out_pc + 3 * (size_t)(wfirst << 2);
            #pragma unroll
            for (int h = 0; h < 3; ++h) {
                const f32x4 v = *reinterpret_cast<const f32x4*>(
                    &lds_pc[wv][256 * h + 4 * lane]);
                __builtin_nontemporal_store(
                    v, reinterpret_cast<f32x4*>(pcw + 256 * h + 4 * lane));
            }
            __builtin_amdgcn_wave_barrier();
        } else {
            // partial wave: direct plain stores (L2 merges strided lines)
            f32x4* pc = reinterpret_cast<f32x4*>(out_pc + 3 * (size_t)base);
            pc[0] = (f32x4){dxv[0], dyv[0], dzv[0], dxv[1]};
            pc[1] = (f32x4){dyv[1], dzv[1], dxv[2], dyv[2]};
            pc[2] = (f32x4){dzv[2], dxv[3], dyv[3], dzv[3]};
        }
    }

    // tail (n_pairs % 4 != 0): scalar fallback
    for (int p = (nbatch << 2) + tid0; p < n_pairs; p += nthr) {
        const int pfs = pair_first[p];
        const int pss = pair_second[p];
        const float f0 = (float)shifts[3 * p + 0];
        const float f1 = (float)shifts[3 * p + 1];
        const float f2 = (float)shifts[3 * p + 2];
        const f32x4 Aa = tab[pfs];
        const f32x4 Bb = tab[pss];
        const float dx = Bb.x - Aa.x + f0 * c00 + f1 * c10 + f2 * c20;
        const float dy = Bb.y - Aa.y + f0 * c01 + f1 * c11 + f2 * c21;
        const float dz = Bb.z - Aa.z + f0 * c02 + f1 * c12 + f2 * c22;
        const float d  = sqrtf(dx * dx + dy * dy + dz * dz);
        const bool  m  = d < HARD_DIST_CUTOFF;
        out_dist[p] = m ? d : 0.0f;
        out_pf[p]   = m ? (float)pfs : -1.0f;
        out_ps[p]   = m ? (float)pss : -1.0f;
        out_pc[3*(size_t)p+0] = m ? dx : 0.0f;
        out_pc[3*(size_t)p+1] = m ? dy : 0.0f;
        out_pc[3*(size_t)p+2] = m ? dz : 0.0f;
        out_mask[p] = m ? 1.0f : 0.0f;
    }
}

// Generic fallback (ws too small for the table):
__global__ __launch_bounds__(256) void external_neighbors_v2(
    const float* __restrict__ coords,
    const int*   __restrict__ real_atoms,
    const int*   __restrict__ shifts,
    const float* __restrict__ cell,
    const int*   __restrict__ pair_first,
    const int*   __restrict__ pair_second,
    float* __restrict__ out,
    int n_pairs)
{
    const float c00 = cell[0], c01 = cell[1], c02 = cell[2];
    const float c10 = cell[3], c11 = cell[4], c12 = cell[5];
    const float c20 = cell[6], c21 = cell[7], c22 = cell[8];
    const size_t N = (size_t)n_pairs;
    float* out_dist = out;
    float* out_pf   = out + N;
    float* out_ps   = out + 2 * N;
    float* out_pc   = out + 3 * N;
    float* out_mask = out + 6 * N;
    const int tid = blockIdx.x * blockDim.x + threadIdx.x;
    const int stride = gridDim.x * blockDim.x;
    for (int p = tid; p < n_pairs; p += stride) {
        const int pfs = pair_first[p];
        const int pss = pair_second[p];
        const float f0 = (float)shifts[3 * p + 0];
        const float f1 = (float)shifts[3 * p + 1];
        const float f2 = (float)shifts[3 * p + 2];
        const int iaa = real_atoms[pfs];
        const int ibb = real_atoms[pss];
        const float dx = coords[3*ibb+0] - coords[3*iaa+0] + f0*c00 + f1*c10 + f2*c20;
        const float dy = coords[3*ibb+1] - coords[3*iaa+1] + f0*c01 + f1*c11 + f2*c21;
        const float dz = coords[3*ibb+2] - coords[3*iaa+2] + f0*c02 + f1*c12 + f2*c22;
        const float d  = sqrtf(dx*dx + dy*dy + dz*dz);
        const bool  m  = d < HARD_DIST_CUTOFF;
        out_dist[p] = m ? d : 0.0f;
        out_pf[p]   = m ? (float)pfs : -1.0f;
        out_ps[p]   = m ? (float)pss : -1.0f;
        out_pc[3*(size_t)p+0] = m ? dx : 0.0f;
        out_pc[3*(size_t)p+1] = m ? dy : 0.0f;
        out_pc[3*(size_t)p+2] = m ? dz : 0.0f;
        out_mask[p] = m ? 1.0f : 0.0f;
    }
}

extern "C" void kernel_launch(void* const* d_in, const int* in_sizes, int n_in,
                              void* d_out, int out_size, void* d_ws, size_t ws_size,
                              hipStream_t stream) {
    const float* coords      = (const float*)d_in[0];  // (128,1024,3) f32
    const int*   real_atoms  = (const int*)d_in[1];    // (131072,) int
    const int*   shifts      = (const int*)d_in[2];    // (8388608,3) int
    const float* cell        = (const float*)d_in[3];  // (3,3) f32
    const int*   pair_first  = (const int*)d_in[4];    // (8388608,) int
    const int*   pair_second = (const int*)d_in[5];    // (8388608,) int
    float*       out         = (float*)d_out;

    const int n_real  = in_sizes[1];  // 131072
    const int n_pairs = in_sizes[4];  // 8388608

    const size_t tab_bytes = (size_t)n_real * sizeof(f32x4);

    if (ws_size >= tab_bytes) {
        f32x4* tab = (f32x4*)d_ws;
        build_gather_table<<<(n_real + 255) / 256, 256, 0, stream>>>(
            coords, real_atoms, tab, n_real);

        // persistent grid-stride: 2048 blocks (8/CU), 4 full iterations each
        external_neighbors_v7<<<2048, 256, 0, stream>>>(
            tab, shifts, cell, pair_first, pair_second, out, n_pairs);
    } else {
        external_neighbors_v2<<<2048, 256, 0, stream>>>(
            coords, real_atoms, shifts, cell, pair_first, pair_second, out, n_pairs);
    }
}

// Round 9
// 415.803 us; speedup vs baseline: 1.0309x; 1.0309x over previous
//
#include <hip/hip_runtime.h>

// ExternalNeighbors: per-pair displacement + periodic shift + cutoff mask.
// Outputs (concatenated flat, all float32):
//   [0N..1N) dist | [1N..2N) pair_first | [2N..3N) pair_second
//   [3N..6N) paircoord (N,3) | [6N..7N) mask
//
// Ledger: v2 231us -> v3 181 (1-hop float4 table) -> v4 169 (NT st)
//   -> v5 251 REGRESS (strided NT partial lines) -> v6 153 (plain ld +
//   NT st + LDS-transposed pc, WRITE exact) -> v7 177 REGRESS (persistent
//   loop serialized iterations; occupancy 67->54).
// v8: v6 one-shot block structure (8192 blocks, 4 pairs/thread) but
// wave-private LDS + wave_barrier instead of __syncthreads -> no
// vmcnt(0)/block-wide drain; LDS write issued before independent NT stores.

typedef float f32x4 __attribute__((ext_vector_type(4)));
typedef int   i32x4 __attribute__((ext_vector_type(4)));

#define HARD_DIST_CUTOFF 2.0f

__global__ __launch_bounds__(256) void build_gather_table(
    const float* __restrict__ coords,      // n_real * 3
    const int*   __restrict__ real_atoms,  // n_real
    f32x4* __restrict__ tab,               // n_real (padded xyz_)
    int n_real)
{
    const int i = blockIdx.x * blockDim.x + threadIdx.x;
    if (i < n_real) {
        const int a = real_atoms[i];
        const float* c = coords + 3 * (size_t)a;
        f32x4 v;
        v.x = c[0]; v.y = c[1]; v.z = c[2]; v.w = 0.0f;
        tab[i] = v;  // plain store: keep table cache-resident for the gathers
    }
}

// Requires n_pairs % 1024 == 0 (exact grid, no tail).
__global__ __launch_bounds__(256) void external_neighbors_v8(
    const f32x4* __restrict__ tab,          // n_real pre-gathered coords
    const int*   __restrict__ shifts,       // n_pairs * 3
    const float* __restrict__ cell,         // 9
    const int*   __restrict__ pair_first,   // n_pairs
    const int*   __restrict__ pair_second,  // n_pairs
    float* __restrict__ out,
    int n_pairs)
{
    __shared__ float lds_pc[4][768];  // per-WAVE 3KB staging for paircoord

    const float c00 = cell[0], c01 = cell[1], c02 = cell[2];
    const float c10 = cell[3], c11 = cell[4], c12 = cell[5];
    const float c20 = cell[6], c21 = cell[7], c22 = cell[8];

    const size_t N = (size_t)n_pairs;
    float* __restrict__ out_dist = out;
    float* __restrict__ out_pf   = out + N;
    float* __restrict__ out_ps   = out + 2 * N;
    float* __restrict__ out_pc   = out + 3 * N;
    float* __restrict__ out_mask = out + 6 * N;

    const int tid  = blockIdx.x * blockDim.x + threadIdx.x;
    const int base = tid << 2;                 // 4 pairs/thread
    const int wv   = threadIdx.x >> 6;         // wave within block
    const int lane = threadIdx.x & 63;

    // ---- plain (cached) stream loads: inputs are L3-warm ----
    const i32x4 pf4 = *reinterpret_cast<const i32x4*>(pair_first  + base);
    const i32x4 ps4 = *reinterpret_cast<const i32x4*>(pair_second + base);
    const i32x4* sh = reinterpret_cast<const i32x4*>(shifts + 3 * (size_t)base);
    const i32x4 sA = sh[0], sB = sh[1], sC = sh[2];

    const int pf[4] = {pf4.x, pf4.y, pf4.z, pf4.w};
    const int ps[4] = {ps4.x, ps4.y, ps4.z, ps4.w};
    const int s0[4] = {sA.x, sA.w, sB.z, sC.y};
    const int s1[4] = {sA.y, sB.x, sB.w, sC.z};
    const int s2[4] = {sA.z, sB.y, sC.x, sC.w};

    // ---- 8 independent 16B gathers (cache-resident table) ----
    f32x4 A[4], B[4];
    #pragma unroll
    for (int k = 0; k < 4; ++k) A[k] = tab[pf[k]];
    #pragma unroll
    for (int k = 0; k < 4; ++k) B[k] = tab[ps[k]];

    // ---- compute ----
    f32x4 dist, pfo, pso, msk;
    float dxv[4], dyv[4], dzv[4];
    #pragma unroll
    for (int k = 0; k < 4; ++k) {
        const float f0 = (float)s0[k], f1 = (float)s1[k], f2 = (float)s2[k];
        const float dx = B[k].x - A[k].x + f0 * c00 + f1 * c10 + f2 * c20;
        const float dy = B[k].y - A[k].y + f0 * c01 + f1 * c11 + f2 * c21;
        const float dz = B[k].z - A[k].z + f0 * c02 + f1 * c12 + f2 * c22;
        const float d  = sqrtf(dx * dx + dy * dy + dz * dz);
        const bool  m  = d < HARD_DIST_CUTOFF;
        dist[k] = m ? d : 0.0f;
        pfo[k]  = m ? (float)pf[k] : -1.0f;
        pso[k]  = m ? (float)ps[k] : -1.0f;
        msk[k]  = m ? 1.0f : 0.0f;
        dxv[k]  = m ? dx : 0.0f;
        dyv[k]  = m ? dy : 0.0f;
        dzv[k]  = m ? dz : 0.0f;
    }

    // ---- LDS staging first (DS round-trip hides under NT store issue) ----
    f32x4* myl = reinterpret_cast<f32x4*>(&lds_pc[wv][12 * lane]);
    myl[0] = (f32x4){dxv[0], dyv[0], dzv[0], dxv[1]};
    myl[1] = (f32x4){dyv[1], dzv[1], dxv[2], dyv[2]};
    myl[2] = (f32x4){dzv[2], dxv[3], dyv[3], dzv[3]};

    // ---- independent NT stores (1KB wave bursts each) ----
    __builtin_nontemporal_store(dist, reinterpret_cast<f32x4*>(out_dist + base));
    __builtin_nontemporal_store(pfo,  reinterpret_cast<f32x4*>(out_pf   + base));
    __builtin_nontemporal_store(pso,  reinterpret_cast<f32x4*>(out_ps   + base));
    __builtin_nontemporal_store(msk,  reinterpret_cast<f32x4*>(out_mask + base));

    // ---- wave-private LDS transpose: wave barrier only, no block drain ----
    __builtin_amdgcn_wave_barrier();  // wave64 lockstep; lgkmcnt orders DS ops
    float* pcw = out_pc + 768 * (size_t)((blockIdx.x << 2) + wv);
    #pragma unroll
    for (int h = 0; h < 3; ++h) {
        const f32x4 v = *reinterpret_cast<const f32x4*>(&lds_pc[wv][256 * h + 4 * lane]);
        __builtin_nontemporal_store(v, reinterpret_cast<f32x4*>(pcw + 256 * h + 4 * lane));
    }
}

// Generic fallback (any n_pairs; also used if ws too small for the table):
__global__ __launch_bounds__(256) void external_neighbors_v2(
    const float* __restrict__ coords,
    const int*   __restrict__ real_atoms,
    const int*   __restrict__ shifts,
    const float* __restrict__ cell,
    const int*   __restrict__ pair_first,
    const int*   __restrict__ pair_second,
    float* __restrict__ out,
    int n_pairs)
{
    const float c00 = cell[0], c01 = cell[1], c02 = cell[2];
    const float c10 = cell[3], c11 = cell[4], c12 = cell[5];
    const float c20 = cell[6], c21 = cell[7], c22 = cell[8];
    const size_t N = (size_t)n_pairs;
    float* out_dist = out;
    float* out_pf   = out + N;
    float* out_ps   = out + 2 * N;
    float* out_pc   = out + 3 * N;
    float* out_mask = out + 6 * N;
    const int tid = blockIdx.x * blockDim.x + threadIdx.x;
    const int stride = gridDim.x * blockDim.x;
    for (int p = tid; p < n_pairs; p += stride) {
        const int pfs = pair_first[p];
        const int pss = pair_second[p];
        const float f0 = (float)shifts[3 * p + 0];
        const float f1 = (float)shifts[3 * p + 1];
        const float f2 = (float)shifts[3 * p + 2];
        const int iaa = real_atoms[pfs];
        const int ibb = real_atoms[pss];
        const float dx = coords[3*ibb+0] - coords[3*iaa+0] + f0*c00 + f1*c10 + f2*c20;
        const float dy = coords[3*ibb+1] - coords[3*iaa+1] + f0*c01 + f1*c11 + f2*c21;
        const float dz = coords[3*ibb+2] - coords[3*iaa+2] + f0*c02 + f1*c12 + f2*c22;
        const float d  = sqrtf(dx*dx + dy*dy + dz*dz);
        const bool  m  = d < HARD_DIST_CUTOFF;
        out_dist[p] = m ? d : 0.0f;
        out_pf[p]   = m ? (float)pfs : -1.0f;
        out_ps[p]   = m ? (float)pss : -1.0f;
        out_pc[3*(size_t)p+0] = m ? dx : 0.0f;
        out_pc[3*(size_t)p+1] = m ? dy : 0.0f;
        out_pc[3*(size_t)p+2] = m ? dz : 0.0f;
        out_mask[p] = m ? 1.0f : 0.0f;
    }
}

extern "C" void kernel_launch(void* const* d_in, const int* in_sizes, int n_in,
                              void* d_out, int out_size, void* d_ws, size_t ws_size,
                              hipStream_t stream) {
    const float* coords      = (const float*)d_in[0];  // (128,1024,3) f32
    const int*   real_atoms  = (const int*)d_in[1];    // (131072,) int
    const int*   shifts      = (const int*)d_in[2];    // (8388608,3) int
    const float* cell        = (const float*)d_in[3];  // (3,3) f32
    const int*   pair_first  = (const int*)d_in[4];    // (8388608,) int
    const int*   pair_second = (const int*)d_in[5];    // (8388608,) int
    float*       out         = (float*)d_out;

    const int n_real  = in_sizes[1];  // 131072
    const int n_pairs = in_sizes[4];  // 8388608

    const size_t tab_bytes = (size_t)n_real * sizeof(f32x4);

    if (ws_size >= tab_bytes && (n_pairs % 1024) == 0) {
        f32x4* tab = (f32x4*)d_ws;
        build_gather_table<<<(n_real + 255) / 256, 256, 0, stream>>>(
            coords, real_atoms, tab, n_real);

        const int grid = n_pairs / 1024;  // 8192 one-shot blocks, exact
        external_neighbors_v8<<<grid, 256, 0, stream>>>(
            tab, shifts, cell, pair_first, pair_second, out, n_pairs);
    } else {
        external_neighbors_v2<<<2048, 256, 0, stream>>>(
            coords, real_atoms, shifts, cell, pair_first, pair_second, out, n_pairs);
    }
}

// Round 10
// 395.867 us; speedup vs baseline: 1.0828x; 1.0504x over previous
//
#include <hip/hip_runtime.h>

// ExternalNeighbors: per-pair displacement + periodic shift + cutoff mask.
// Outputs (concatenated flat, all float32):
//   [0N..1N) dist | [1N..2N) pair_first | [2N..3N) pair_second
//   [3N..6N) paircoord (N,3) | [6N..7N) mask
//
// Ledger: v2 231us -> v3 181 (1-hop float4 table) -> v4 169 (NT st)
//   -> v5 251 REGRESS (strided NT partial lines) -> v6 153 (plain ld +
//   NT st + LDS pc transpose, WRITE exact) -> v7 177 REGRESS (persistent
//   loop) -> v8 161 (wave_barrier reorder: no better than v6).
// v9: v6's exact store pattern, but TWO independent 4-pair batches per
// thread (b and b+nbatch/2) -> 16 independent gathers in flight. Tests
// latency-exposure vs request-throughput as the remaining ceiling.

typedef float f32x4 __attribute__((ext_vector_type(4)));
typedef int   i32x4 __attribute__((ext_vector_type(4)));

#define HARD_DIST_CUTOFF 2.0f

__global__ __launch_bounds__(256) void build_gather_table(
    const float* __restrict__ coords,      // n_real * 3
    const int*   __restrict__ real_atoms,  // n_real
    f32x4* __restrict__ tab,               // n_real (padded xyz_)
    int n_real)
{
    const int i = blockIdx.x * blockDim.x + threadIdx.x;
    if (i < n_real) {
        const int a = real_atoms[i];
        const float* c = coords + 3 * (size_t)a;
        f32x4 v;
        v.x = c[0]; v.y = c[1]; v.z = c[2]; v.w = 0.0f;
        tab[i] = v;  // plain store: keep table cache-resident for the gathers
    }
}

// Requires n_pairs % 2048 == 0 (exact grid, two batches/thread, no tail).
__global__ __launch_bounds__(256) void external_neighbors_v9(
    const f32x4* __restrict__ tab,          // n_real pre-gathered coords
    const int*   __restrict__ shifts,       // n_pairs * 3
    const float* __restrict__ cell,         // 9
    const int*   __restrict__ pair_first,   // n_pairs
    const int*   __restrict__ pair_second,  // n_pairs
    float* __restrict__ out,
    int n_pairs)
{
    __shared__ float lds_pc[2][4][768];  // [batch][wave] 3KB staging for pc

    const float c00 = cell[0], c01 = cell[1], c02 = cell[2];
    const float c10 = cell[3], c11 = cell[4], c12 = cell[5];
    const float c20 = cell[6], c21 = cell[7], c22 = cell[8];

    const size_t N = (size_t)n_pairs;
    float* __restrict__ out_dist = out;
    float* __restrict__ out_pf   = out + N;
    float* __restrict__ out_ps   = out + 2 * N;
    float* __restrict__ out_pc   = out + 3 * N;
    float* __restrict__ out_mask = out + 6 * N;

    const int tid  = blockIdx.x * blockDim.x + threadIdx.x;
    const int H    = n_pairs >> 3;             // nbatch/2 (batches of 4)
    const int wv   = threadIdx.x >> 6;
    const int lane = threadIdx.x & 63;

    const int bidx[2]  = {tid, tid + H};

    // ---- plain (cached) coalesced loads for both batches ----
    i32x4 pf4[2], ps4[2], sA[2], sB[2], sC[2];
    #pragma unroll
    for (int j = 0; j < 2; ++j) {
        const int base = bidx[j] << 2;
        pf4[j] = *reinterpret_cast<const i32x4*>(pair_first  + base);
        ps4[j] = *reinterpret_cast<const i32x4*>(pair_second + base);
        const i32x4* sh = reinterpret_cast<const i32x4*>(shifts + 3 * (size_t)base);
        sA[j] = sh[0]; sB[j] = sh[1]; sC[j] = sh[2];
    }

    int pf[2][4], ps[2][4], s0[2][4], s1[2][4], s2[2][4];
    #pragma unroll
    for (int j = 0; j < 2; ++j) {
        pf[j][0]=pf4[j].x; pf[j][1]=pf4[j].y; pf[j][2]=pf4[j].z; pf[j][3]=pf4[j].w;
        ps[j][0]=ps4[j].x; ps[j][1]=ps4[j].y; ps[j][2]=ps4[j].z; ps[j][3]=ps4[j].w;
        s0[j][0]=sA[j].x; s0[j][1]=sA[j].w; s0[j][2]=sB[j].z; s0[j][3]=sC[j].y;
        s1[j][0]=sA[j].y; s1[j][1]=sB[j].x; s1[j][2]=sB[j].w; s1[j][3]=sC[j].z;
        s2[j][0]=sA[j].z; s2[j][1]=sB[j].y; s2[j][2]=sC[j].x; s2[j][3]=sC[j].w;
    }

    // ---- 16 independent 16B gathers (cache-resident table) ----
    f32x4 A[2][4], B[2][4];
    #pragma unroll
    for (int j = 0; j < 2; ++j) {
        #pragma unroll
        for (int k = 0; k < 4; ++k) A[j][k] = tab[pf[j][k]];
    }
    #pragma unroll
    for (int j = 0; j < 2; ++j) {
        #pragma unroll
        for (int k = 0; k < 4; ++k) B[j][k] = tab[ps[j][k]];
    }

    // ---- compute + coalesced NT stores + LDS staging, per batch ----
    #pragma unroll
    for (int j = 0; j < 2; ++j) {
        const int base = bidx[j] << 2;
        f32x4 dist, pfo, pso, msk;
        float dxv[4], dyv[4], dzv[4];
        #pragma unroll
        for (int k = 0; k < 4; ++k) {
            const float f0 = (float)s0[j][k], f1 = (float)s1[j][k], f2 = (float)s2[j][k];
            const float dx = B[j][k].x - A[j][k].x + f0 * c00 + f1 * c10 + f2 * c20;
            const float dy = B[j][k].y - A[j][k].y + f0 * c01 + f1 * c11 + f2 * c21;
            const float dz = B[j][k].z - A[j][k].z + f0 * c02 + f1 * c12 + f2 * c22;
            const float d  = sqrtf(dx * dx + dy * dy + dz * dz);
            const bool  m  = d < HARD_DIST_CUTOFF;
            dist[k] = m ? d : 0.0f;
            pfo[k]  = m ? (float)pf[j][k] : -1.0f;
            pso[k]  = m ? (float)ps[j][k] : -1.0f;
            msk[k]  = m ? 1.0f : 0.0f;
            dxv[k]  = m ? dx : 0.0f;
            dyv[k]  = m ? dy : 0.0f;
            dzv[k]  = m ? dz : 0.0f;
        }

        __builtin_nontemporal_store(dist, reinterpret_cast<f32x4*>(out_dist + base));
        __builtin_nontemporal_store(pfo,  reinterpret_cast<f32x4*>(out_pf   + base));
        __builtin_nontemporal_store(pso,  reinterpret_cast<f32x4*>(out_ps   + base));
        __builtin_nontemporal_store(msk,  reinterpret_cast<f32x4*>(out_mask + base));

        f32x4* myl = reinterpret_cast<f32x4*>(&lds_pc[j][wv][12 * lane]);
        myl[0] = (f32x4){dxv[0], dyv[0], dzv[0], dxv[1]};
        myl[1] = (f32x4){dyv[1], dzv[1], dxv[2], dyv[2]};
        myl[2] = (f32x4){dzv[2], dxv[3], dyv[3], dzv[3]};
    }

    __syncthreads();

    // ---- paircoord: wave-contiguous NT bursts from LDS, both batches ----
    #pragma unroll
    for (int j = 0; j < 2; ++j) {
        const int wfirst = bidx[j] - lane;  // wave's first batch index
        float* pcw = out_pc + 12 * (size_t)wfirst;
        #pragma unroll
        for (int h = 0; h < 3; ++h) {
            const f32x4 v = *reinterpret_cast<const f32x4*>(
                &lds_pc[j][wv][256 * h + 4 * lane]);
            __builtin_nontemporal_store(
                v, reinterpret_cast<f32x4*>(pcw + 256 * h + 4 * lane));
        }
    }
}

// Generic fallback (any n_pairs; also used if ws too small for the table):
__global__ __launch_bounds__(256) void external_neighbors_v2(
    const float* __restrict__ coords,
    const int*   __restrict__ real_atoms,
    const int*   __restrict__ shifts,
    const float* __restrict__ cell,
    const int*   __restrict__ pair_first,
    const int*   __restrict__ pair_second,
    float* __restrict__ out,
    int n_pairs)
{
    const float c00 = cell[0], c01 = cell[1], c02 = cell[2];
    const float c10 = cell[3], c11 = cell[4], c12 = cell[5];
    const float c20 = cell[6], c21 = cell[7], c22 = cell[8];
    const size_t N = (size_t)n_pairs;
    float* out_dist = out;
    float* out_pf   = out + N;
    float* out_ps   = out + 2 * N;
    float* out_pc   = out + 3 * N;
    float* out_mask = out + 6 * N;
    const int tid = blockIdx.x * blockDim.x + threadIdx.x;
    const int stride = gridDim.x * blockDim.x;
    for (int p = tid; p < n_pairs; p += stride) {
        const int pfs = pair_first[p];
        const int pss = pair_second[p];
        const float f0 = (float)shifts[3 * p + 0];
        const float f1 = (float)shifts[3 * p + 1];
        const float f2 = (float)shifts[3 * p + 2];
        const int iaa = real_atoms[pfs];
        const int ibb = real_atoms[pss];
        const float dx = coords[3*ibb+0] - coords[3*iaa+0] + f0*c00 + f1*c10 + f2*c20;
        const float dy = coords[3*ibb+1] - coords[3*iaa+1] + f0*c01 + f1*c11 + f2*c21;
        const float dz = coords[3*ibb+2] - coords[3*iaa+2] + f0*c02 + f1*c12 + f2*c22;
        const float d  = sqrtf(dx*dx + dy*dy + dz*dz);
        const bool  m  = d < HARD_DIST_CUTOFF;
        out_dist[p] = m ? d : 0.0f;
        out_pf[p]   = m ? (float)pfs : -1.0f;
        out_ps[p]   = m ? (float)pss : -1.0f;
        out_pc[3*(size_t)p+0] = m ? dx : 0.0f;
        out_pc[3*(size_t)p+1] = m ? dy : 0.0f;
        out_pc[3*(size_t)p+2] = m ? dz : 0.0f;
        out_mask[p] = m ? 1.0f : 0.0f;
    }
}

extern "C" void kernel_launch(void* const* d_in, const int* in_sizes, int n_in,
                              void* d_out, int out_size, void* d_ws, size_t ws_size,
                              hipStream_t stream) {
    const float* coords      = (const float*)d_in[0];  // (128,1024,3) f32
    const int*   real_atoms  = (const int*)d_in[1];    // (131072,) int
    const int*   shifts      = (const int*)d_in[2];    // (8388608,3) int
    const float* cell        = (const float*)d_in[3];  // (3,3) f32
    const int*   pair_first  = (const int*)d_in[4];    // (8388608,) int
    const int*   pair_second = (const int*)d_in[5];    // (8388608,) int
    float*       out         = (float*)d_out;

    const int n_real  = in_sizes[1];  // 131072
    const int n_pairs = in_sizes[4];  // 8388608

    const size_t tab_bytes = (size_t)n_real * sizeof(f32x4);

    if (ws_size >= tab_bytes && (n_pairs % 2048) == 0) {
        f32x4* tab = (f32x4*)d_ws;
        build_gather_table<<<(n_real + 255) / 256, 256, 0, stream>>>(
            coords, real_atoms, tab, n_real);

        // 2 batches/thread: threads = n_pairs/8 -> blocks = n_pairs/2048 (4096)
        const int grid = n_pairs / 2048;
        external_neighbors_v9<<<grid, 256, 0, stream>>>(
            tab, shifts, cell, pair_first, pair_second, out, n_pairs);
    } else {
        external_neighbors_v2<<<2048, 256, 0, stream>>>(
            coords, real_atoms, shifts, cell, pair_first, pair_second, out, n_pairs);
    }
}